// Round 10
// baseline (103.382 us; speedup 1.0000x reference)
//
#include <hip/hip_runtime.h>
#include <hip/hip_bf16.h>

#define B_    32
#define C_    128
#define H_    56
#define W_    56
#define N_    3136
#define HK_   15
#define NK_   225
#define D_    64

typedef __attribute__((ext_vector_type(8))) short bf16x8;
typedef __attribute__((ext_vector_type(4))) float f32x4;

__device__ __forceinline__ float b2f(unsigned short u) {
    union { float f; unsigned int i; } x;
    x.i = ((unsigned int)u) << 16;
    return x.f;
}
__device__ __forceinline__ unsigned short f2b(float f) {
    __hip_bfloat16 h = __float2bfloat16(f);
    return *(unsigned short*)&h;
}

// async global -> LDS, 16B/lane; LDS dest wave-uniform base (HW adds lane*16)
__device__ __forceinline__ void gll16(const char* g, char* l) {
    __builtin_amdgcn_global_load_lds(
        (const __attribute__((address_space(1))) unsigned int*)g,
        (__attribute__((address_space(3))) unsigned int*)l,
        16, 0, 0);
}

// ---------------- Kernel 1: fused sr + local conv ----------------
__global__ __launch_bounds__(256) void srlocal_kernel(
        const float* __restrict__ x,
        const float* __restrict__ sr1_w, const float* __restrict__ sr1_g,
        const float* __restrict__ sr1_b, const float* __restrict__ sr1_m,
        const float* __restrict__ sr1_v, const float* __restrict__ sr2_w,
        const float* __restrict__ sr2_g, const float* __restrict__ sr2_b,
        const float* __restrict__ sr2_m, const float* __restrict__ sr2_v,
        const float* __restrict__ local_w, const float* __restrict__ local_b,
        float* __restrict__ kv2) {
    int bc = blockIdx.x;
    int c  = bc & (C_ - 1);
    int tid = threadIdx.x;
    __shared__ float xim[H_ * W_];
    __shared__ float kvt[HK_][HK_ + 1];

    const float* xp = x + (size_t)bc * (H_ * W_);
    for (int idx = tid; idx < (H_ * W_) / 4; idx += 256)
        ((float4*)xim)[idx] = ((const float4*)xp)[idx];
    __syncthreads();

    int p = tid;
    int oy = p / HK_, ox = p % HK_;
    if (p < NK_) {
        float s = 0.f;
#pragma unroll
        for (int ky = 0; ky < 4; ++ky) {
            int iy = oy * 4 - 2 + ky;
            if (iy < 0 || iy >= H_) continue;
#pragma unroll
            for (int kx = 0; kx < 4; ++kx) {
                int ix = ox * 4 - 2 + kx;
                if (ix < 0 || ix >= W_) continue;
                s += xim[iy * W_ + ix] * sr1_w[c * 16 + ky * 4 + kx];
            }
        }
        float inv1 = sr1_g[c] * rsqrtf(sr1_v[c] + 1e-5f);
        s = (s - sr1_m[c]) * inv1 + sr1_b[c];
        s = fmaxf(s, 0.f);
        s *= sr2_w[c];
        float inv2 = sr2_g[c] * rsqrtf(sr2_v[c] + 1e-5f);
        s = (s - sr2_m[c]) * inv2 + sr2_b[c];
        kvt[oy][ox] = s;
    }
    __syncthreads();
    if (p < NK_) {
        float v = kvt[oy][ox] + local_b[c];
#pragma unroll
        for (int dy = -1; dy <= 1; ++dy) {
            int yy = oy + dy;
            if (yy < 0 || yy >= HK_) continue;
#pragma unroll
            for (int dx = -1; dx <= 1; ++dx) {
                int xx = ox + dx;
                if (xx < 0 || xx >= HK_) continue;
                v += kvt[yy][xx] * local_w[c * 9 + (dy + 1) * 3 + (dx + 1)];
            }
        }
        kv2[(size_t)bc * NK_ + p] = v;
    }
}

// ---------------- Kernel 0: weight prep ----------------
__global__ __launch_bounds__(256) void wprep_kernel(
        const float* __restrict__ q_w, const float* __restrict__ q_b,
        const float* __restrict__ kv_w, const float* __restrict__ kv_b,
        unsigned short* __restrict__ wkq_sw, unsigned short* __restrict__ wv_sw,
        float* __restrict__ kwb, float* __restrict__ wb, float* __restrict__ qkb) {
    int bx = blockIdx.x;          // 0..15
    int h  = bx >> 3, cg = bx & 7;
    int tid = threadIdx.x;
    __shared__ float wk_s[64][128];
    __shared__ float wq_s[64][16];

    for (int idx = tid; idx < 64 * 128; idx += 256)
        wk_s[idx >> 7][idx & 127] = kv_w[(size_t)(h * 64 + (idx >> 7)) * 128 + (idx & 127)];
    for (int idx = tid; idx < 64 * 16; idx += 256)
        wq_s[idx >> 4][idx & 15] = q_w[(size_t)(h * 64 + (idx >> 4)) * 128 + cg * 16 + (idx & 15)];
    __syncthreads();

    {
        int cl = tid >> 4;
        int c  = cg * 16 + cl;
        int cp0 = (tid & 15) * 8;
        float acc[8];
#pragma unroll
        for (int i = 0; i < 8; ++i) acc[i] = 0.f;
        for (int e = 0; e < 64; ++e) {
            float wqv = wq_s[e][cl];
#pragma unroll
            for (int i = 0; i < 8; ++i) acc[i] += wqv * wk_s[e][cp0 + i];
        }
        char* base = (char*)wkq_sw + (size_t)h * 32768 + (size_t)c * 256;
        ushort4 u0, u1;
        u0.x = f2b(acc[0] * 0.125f); u0.y = f2b(acc[1] * 0.125f);
        u0.z = f2b(acc[2] * 0.125f); u0.w = f2b(acc[3] * 0.125f);
        u1.x = f2b(acc[4] * 0.125f); u1.y = f2b(acc[5] * 0.125f);
        u1.z = f2b(acc[6] * 0.125f); u1.w = f2b(acc[7] * 0.125f);
        int sw = (c & 7) << 4;
        *(ushort4*)(base + ((cp0 * 2) ^ sw)) = u0;
        *(ushort4*)(base + ((cp0 * 2 + 8) ^ sw)) = u1;
    }
    if (tid < 16) {
        int cl = tid, c = cg * 16 + cl;
        float s = 0.f;
        for (int e = 0; e < 64; ++e) s += kv_b[h * 64 + e] * wq_s[e][cl];
        kwb[h * 128 + c] = s * 0.125f;
    }
    if (cg == 0) {
        if (tid < 128) {
            float s = 0.f;
            for (int e = 0; e < 64; ++e) s += q_b[h * 64 + e] * wk_s[e][tid];
            wb[h * 128 + tid] = s * 0.125f;
        }
        if (tid == 0) {
            float s = 0.f;
            for (int e = 0; e < 64; ++e) s += q_b[h * 64 + e] * kv_b[h * 64 + e];
            qkb[h] = s * 0.125f;
        }
    }
    if (cg == 1) {
        for (int idx = tid; idx < 64 * 128; idx += 256) {
            int e = idx >> 7, cp = idx & 127;
            unsigned short val = f2b(kv_w[(size_t)(128 + h * 64 + e) * 128 + cp]);
            *(unsigned short*)((char*)wv_sw + (size_t)h * 16384 + (size_t)e * 256 +
                               (((cp * 2) ^ ((e & 7) << 4)))) = val;
        }
    }
}

// ---------------- Kernel 2: kv projection via folded weights, MFMA ----------------
// kw:     [bh][256 rows m][256B c], bf16 swizzled
// bias_s: [bh][256] f32, -1e30 for m>=225
// vbuf:   [bh][64 rows e][512B m], bf16 swizzled
#define L2B(r, cb) ((r) * 256 + ((cb) ^ (((r) & 7) << 4)))
__global__ __launch_bounds__(256, 2) void kvw_kernel(
        const float* __restrict__ kv2,
        const float* __restrict__ kv_b,
        const unsigned short* __restrict__ wkq_sw,
        const unsigned short* __restrict__ wv_sw,
        const float* __restrict__ kwb,
        const float* __restrict__ wb,
        const float* __restrict__ qkb,
        unsigned short* __restrict__ kw,
        float* __restrict__ bias_s,
        unsigned short* __restrict__ vbuf) {
    int b = blockIdx.x, h = blockIdx.y, mh = blockIdx.z;
    int bh = b * 2 + h;
    int m0 = mh * 64;
    int tid = threadIdx.x;
    int lo = tid & 15, hi = (tid >> 4) & 3, wid = tid >> 6;

    __shared__ char K2[16384];
    __shared__ char WQ[32768];
    __shared__ char WV[16384];

    {
        const char* srcQ = (const char*)wkq_sw + (size_t)h * 32768 + tid * 16;
        char* dstQ = WQ + wid * 1024;
#pragma unroll
        for (int i = 0; i < 8; ++i) gll16(srcQ + i * 4096, dstQ + i * 4096);
        const char* srcV = (const char*)wv_sw + (size_t)h * 16384 + tid * 16;
        char* dstV = WV + wid * 1024;
#pragma unroll
        for (int i = 0; i < 4; ++i) gll16(srcV + i * 4096, dstV + i * 4096);
    }
    {
        int j = tid & 63;
        int mg = m0 + j;
        bool val = (mg < NK_);
#pragma unroll
        for (int it = 0; it < 8; ++it) {
            int c0 = (tid >> 6) * 4 + it * 16;
            ushort4 u;
            if (val) {
                const float* kp = kv2 + ((size_t)b * 128 + c0) * NK_ + mg;
                u.x = f2b(kp[0]);
                u.y = f2b(kp[NK_]);
                u.z = f2b(kp[2 * NK_]);
                u.w = f2b(kp[3 * NK_]);
            } else { u.x = 0; u.y = 0; u.z = 0; u.w = 0; }
            *(ushort4*)(K2 + L2B(j, c0 * 2)) = u;
        }
    }
    __syncthreads();

    bf16x8 aq[4];
#pragma unroll
    for (int ks = 0; ks < 4; ++ks)
        aq[ks] = *(const bf16x8*)(K2 + L2B(wid * 16 + lo, ks * 64 + hi * 16));

    char* kwB = (char*)kw + (size_t)bh * 65536;
#pragma unroll
    for (int ct = 0; ct < 8; ++ct) {
        f32x4 acc = {0.f, 0.f, 0.f, 0.f};
#pragma unroll
        for (int ks = 0; ks < 4; ++ks) {
            bf16x8 bq = *(const bf16x8*)(WQ + L2B(ct * 16 + lo, ks * 64 + hi * 16));
            acc = __builtin_amdgcn_mfma_f32_16x16x32_bf16(aq[ks], bq, acc, 0, 0, 0);
        }
        int c = ct * 16 + lo;
        float kb = kwb[h * 128 + c];
#pragma unroll
        for (int r = 0; r < 4; ++r) {
            int mg = m0 + wid * 16 + hi * 4 + r;
            *(unsigned short*)(kwB + (size_t)mg * 256 + (((c * 2) ^ ((mg & 7) << 4)))) =
                f2b(acc[r] + kb);
        }
    }

    char* vB = (char*)vbuf + (size_t)bh * 32768;
#pragma unroll
    for (int et = 0; et < 4; ++et) {
        f32x4 acc = {0.f, 0.f, 0.f, 0.f};
#pragma unroll
        for (int ks = 0; ks < 4; ++ks) {
            bf16x8 bv = *(const bf16x8*)(WV + L2B(et * 16 + lo, ks * 64 + hi * 16));
            acc = __builtin_amdgcn_mfma_f32_16x16x32_bf16(aq[ks], bv, acc, 0, 0, 0);
        }
        int e = et * 16 + lo;
        float vb = kv_b[128 + h * 64 + e];
#pragma unroll
        for (int r = 0; r < 4; ++r) {
            int mg = m0 + wid * 16 + hi * 4 + r;
            *(unsigned short*)(vB + (size_t)e * 512 + (((mg * 2) ^ ((e & 7) << 4)))) =
                f2b(acc[r] + vb);
        }
    }

    if (tid < 64) {
        int mg = m0 + tid;
        float s;
        if (mg >= NK_) s = -1e30f;
        else {
            s = qkb[h];
            for (int i = 0; i < 128; ++i) {
                int cp = (i + (tid & 7) * 16) & 127;
                s += b2f(*(const unsigned short*)(K2 + L2B(tid, cp * 2))) * wb[h * 128 + cp];
            }
        }
        bias_s[(size_t)bh * 256 + mg] = s;
    }
}

// ---------------- Kernel 3: fused attention, XCD-pinned + LDS-fed pipelined ----------------
#define XTB(j, c) ((j) * 256 + (((c) * 2) ^ (((j) & 15) << 4)))
#define PSB(j, m) ((j) * 512 + (((m) * 2) ^ (((j) & 15) << 4)))
#define KWB(rl, cb) ((rl) * 256 + ((cb) ^ (((rl) & 7) << 4)))
#define CVB(e, cb)  ((e) * 512 + ((cb) ^ (((e) & 7) << 4)))

__global__ __launch_bounds__(256, 2) void attn_kernel(
        const float* __restrict__ x,
        const unsigned short* __restrict__ kw,
        const float* __restrict__ bias_s,
        const unsigned short* __restrict__ vbuf,
        float* __restrict__ out) {
    // XCD-pinned decode: all 49 j-tiles of a given bh land on one XCD
    int flat = blockIdx.x;              // 0..3135
    int xcd  = flat & 7;
    int idx  = flat >> 3;               // 0..391
    int g    = idx / 49;                // 0..7
    int jt   = idx % 49;
    int bh   = g * 8 + xcd;
    int bb   = bh >> 1;
    int h    = bh & 1;
    int n0   = jt * 64;
    int tid = threadIdx.x;
    int lo  = tid & 15;
    int hi  = (tid >> 4) & 3;
    int wid = tid >> 6;
    int jw  = wid * 16;

    __shared__ char A[32768];      // xt (16KB) then ps (32KB)
    __shared__ char Bt[2][8192];   // kw tile double-buffer: 32 rows x 256B
    __shared__ char Cv[32768];     // v: 64 rows x 512B, swizzled

    const char* kwG = (const char*)kw + (size_t)bh * 65536;
    const char* vG  = (const char*)vbuf + (size_t)bh * 32768;

    // ---- prologue: xt scalar stage + bias regs issued FIRST (vmcnt ledger: older-than-needed is safe) ----
#pragma unroll
    for (int it = 0; it < 8; ++it) {
        int j  = tid & 63;
        int c0 = (tid >> 6) * 4 + it * 16;
        const float* xp = x + ((size_t)bb * 128 + c0) * N_ + n0 + j;
        ushort4 u;
        u.x = f2b(xp[0]);
        u.y = f2b(xp[(size_t)N_]);
        u.z = f2b(xp[2 * (size_t)N_]);
        u.w = f2b(xp[3 * (size_t)N_]);
        *(ushort4*)(A + XTB(j, c0)) = u;
    }
    float bs[16];
    {
        const float* bsp = bias_s + (size_t)bh * 256;
#pragma unroll
        for (int mt = 0; mt < 16; ++mt) bs[mt] = bsp[mt * 16 + lo];
    }
    // gll16 ledger: kw0(2), kw1(2), cv(8)
    {
        const char* s0 = kwG + tid * 16;
        char* d0 = Bt[0] + wid * 1024;
        gll16(s0, d0); gll16(s0 + 4096, d0 + 4096);
        const char* s1 = kwG + 8192 + tid * 16;
        char* d1 = Bt[1] + wid * 1024;
        gll16(s1, d1); gll16(s1 + 4096, d1 + 4096);
        const char* sc = vG + tid * 16;
        char* dc = Cv + wid * 1024;
#pragma unroll
        for (int i = 0; i < 8; ++i) gll16(sc + i * 4096, dc + i * 4096);
    }
    // need kw0 + xt writes; kw1(2)+cv(8) may stay in flight
    asm volatile("s_waitcnt vmcnt(10) lgkmcnt(0)" ::: "memory");
    __builtin_amdgcn_s_barrier();
    __builtin_amdgcn_sched_barrier(0);

    bf16x8 aq[4];
#pragma unroll
    for (int ks = 0; ks < 4; ++ks)
        aq[ks] = *(const bf16x8*)(A + XTB(jw + lo, ks * 32 + hi * 8));

    // ---- S loop: 8 tiles x 32 m-rows, double-buffered, counted vmcnt ----
    f32x4 s[16];
#pragma unroll
    for (int t = 0; t < 8; ++t) {
#pragma unroll
        for (int ml = 0; ml < 2; ++ml) {
            f32x4 acc = {0.f, 0.f, 0.f, 0.f};
#pragma unroll
            for (int ks = 0; ks < 4; ++ks) {
                bf16x8 bk = *(const bf16x8*)(Bt[t & 1] + KWB(ml * 16 + lo, ks * 64 + hi * 16));
                acc = __builtin_amdgcn_mfma_f32_16x16x32_bf16(aq[ks], bk, acc, 0, 0, 0);
            }
            s[t * 2 + ml] = acc;
        }
        if (t < 6) {
            __builtin_amdgcn_s_barrier();              // all waves done reading Bt[t&1]
            const char* sn = kwG + (t + 2) * 8192 + tid * 16;
            char* dn = Bt[t & 1] + wid * 1024;
            gll16(sn, dn); gll16(sn + 4096, dn + 4096);
        }
        if (t < 7) {
            if (t == 0)      asm volatile("s_waitcnt vmcnt(10)" ::: "memory");
            else if (t < 6)  asm volatile("s_waitcnt vmcnt(2)" ::: "memory");
            else             asm volatile("s_waitcnt vmcnt(0)" ::: "memory");
            __builtin_amdgcn_s_barrier();
            __builtin_amdgcn_sched_barrier(0);
        }
    }

    // ---- bias add + softmax (masked cols carry -1e30 bias -> exp 0) ----
#pragma unroll
    for (int mt = 0; mt < 16; ++mt) {
#pragma unroll
        for (int r = 0; r < 4; ++r) s[mt][r] += bs[mt];
    }
    float mx[4];
#pragma unroll
    for (int r = 0; r < 4; ++r) {
        float m0v = s[0][r];
#pragma unroll
        for (int mt = 1; mt < 16; ++mt) m0v = fmaxf(m0v, s[mt][r]);
        mx[r] = m0v;
    }
#pragma unroll
    for (int d = 1; d < 16; d <<= 1) {
#pragma unroll
        for (int r = 0; r < 4; ++r) mx[r] = fmaxf(mx[r], __shfl_xor(mx[r], d));
    }
    float sm[4] = {0.f, 0.f, 0.f, 0.f};
#pragma unroll
    for (int mt = 0; mt < 16; ++mt) {
#pragma unroll
        for (int r = 0; r < 4; ++r) {
            float pe = __expf(s[mt][r] - mx[r]);
            s[mt][r] = pe;
            sm[r] += pe;
        }
    }
#pragma unroll
    for (int d = 1; d < 16; d <<= 1) {
#pragma unroll
        for (int r = 0; r < 4; ++r) sm[r] += __shfl_xor(sm[r], d);
    }
    float rinv[4];
#pragma unroll
    for (int r = 0; r < 4; ++r) rinv[r] = 1.f / sm[r];

    // normalized P -> ps (wave-private rows; aq already consumed by all waves pre-S-loop,
    // and in-loop barriers guarantee every wave is past the xt region)
#pragma unroll
    for (int mt = 0; mt < 16; ++mt) {
#pragma unroll
        for (int r = 0; r < 4; ++r)
            *(unsigned short*)(A + PSB(jw + hi * 4 + r, mt * 16 + lo)) =
                f2b(s[mt][r] * rinv[r]);
    }

    // ---- PV: O^T[e][j] = V^T[e][m] . P[j][m]; A-frags from Cv LDS, B-frags own ps rows ----
    bf16x8 bp[8];
#pragma unroll
    for (int ks = 0; ks < 8; ++ks)
        bp[ks] = *(const bf16x8*)(A + PSB(jw + lo, ks * 32 + hi * 8));
#pragma unroll
    for (int et = 0; et < 4; ++et) {
        f32x4 acc = {0.f, 0.f, 0.f, 0.f};
#pragma unroll
        for (int ks = 0; ks < 8; ++ks) {
            bf16x8 av = *(const bf16x8*)(Cv + CVB(et * 16 + lo, ks * 64 + hi * 16));
            acc = __builtin_amdgcn_mfma_f32_16x16x32_bf16(av, bp[ks], acc, 0, 0, 0);
        }
        int e = et * 16 + hi * 4;
#pragma unroll
        for (int r = 0; r < 4; ++r)
            out[((size_t)bb * 128 + h * 64 + e + r) * N_ + n0 + jw + lo] = acc[r];
    }
}

extern "C" void kernel_launch(void* const* d_in, const int* in_sizes, int n_in,
                              void* d_out, int out_size, void* d_ws, size_t ws_size,
                              hipStream_t stream) {
    const float* x       = (const float*)d_in[0];
    const float* q_w     = (const float*)d_in[1];
    const float* q_b     = (const float*)d_in[2];
    const float* kv_w    = (const float*)d_in[3];
    const float* kv_b    = (const float*)d_in[4];
    const float* sr1_w   = (const float*)d_in[5];
    const float* sr1_g   = (const float*)d_in[6];
    const float* sr1_b   = (const float*)d_in[7];
    const float* sr1_m   = (const float*)d_in[8];
    const float* sr1_v   = (const float*)d_in[9];
    const float* sr2_w   = (const float*)d_in[10];
    const float* sr2_g   = (const float*)d_in[11];
    const float* sr2_b   = (const float*)d_in[12];
    const float* sr2_m   = (const float*)d_in[13];
    const float* sr2_v   = (const float*)d_in[14];
    const float* local_w = (const float*)d_in[15];
    const float* local_b = (const float*)d_in[16];

    char* ws = (char*)d_ws;
    float* kv2              = (float*)(ws + 0);                 // 3,686,400 B
    unsigned short* wkq_sw  = (unsigned short*)(ws + 3686400);  //    65,536 B
    unsigned short* wv_sw   = (unsigned short*)(ws + 3751936);  //    32,768 B
    unsigned short* kw      = (unsigned short*)(ws + 3784704);  // 4,194,304 B
    unsigned short* vbuf    = (unsigned short*)(ws + 7979008);  // 2,097,152 B
    float* bias_s           = (float*)(ws + 10076160);          //    65,536 B
    float* kwb              = (float*)(ws + 10141696);          //     1,024 B
    float* wb               = (float*)(ws + 10142720);          //     1,024 B
    float* qkb              = (float*)(ws + 10143744);          //         8 B

    wprep_kernel<<<16, 256, 0, stream>>>(q_w, q_b, kv_w, kv_b,
                                         wkq_sw, wv_sw, kwb, wb, qkb);
    srlocal_kernel<<<B_ * C_, 256, 0, stream>>>(
        x, sr1_w, sr1_g, sr1_b, sr1_m, sr1_v,
        sr2_w, sr2_g, sr2_b, sr2_m, sr2_v, local_w, local_b, kv2);
    kvw_kernel<<<dim3(B_, 2, 4), 256, 0, stream>>>(
        kv2, kv_b, wkq_sw, wv_sw, kwb, wb, qkb, kw, bias_s, vbuf);
    attn_kernel<<<3136, 256, 0, stream>>>(
        x, kw, bias_s, vbuf, (float*)d_out);
}

// Round 12
// 89.488 us; speedup vs baseline: 1.1553x; 1.1553x over previous
//
#include <hip/hip_runtime.h>
#include <hip/hip_bf16.h>

#define B_    32
#define C_    128
#define H_    56
#define W_    56
#define N_    3136
#define HK_   15
#define NK_   225
#define D_    64

typedef __attribute__((ext_vector_type(8))) short bf16x8;
typedef __attribute__((ext_vector_type(4))) float f32x4;

__device__ __forceinline__ float b2f(unsigned short u) {
    union { float f; unsigned int i; } x;
    x.i = ((unsigned int)u) << 16;
    return x.f;
}
__device__ __forceinline__ unsigned short f2b(float f) {
    __hip_bfloat16 h = __float2bfloat16(f);
    return *(unsigned short*)&h;
}
__device__ __forceinline__ unsigned int pkbf(float a, float b) {
    return (unsigned int)f2b(a) | ((unsigned int)f2b(b) << 16);
}

// async global -> LDS, 16B/lane; LDS dest wave-uniform base (HW adds lane*16)
__device__ __forceinline__ void gll16(const char* g, char* l) {
    __builtin_amdgcn_global_load_lds(
        (const __attribute__((address_space(1))) unsigned int*)g,
        (__attribute__((address_space(3))) unsigned int*)l,
        16, 0, 0);
}

// ---------------- Kernel 1: fused sr + local conv, with wprep merged (blocks >= 4096) ----
__global__ __launch_bounds__(256) void prep_kernel(
        const float* __restrict__ x,
        const float* __restrict__ sr1_w, const float* __restrict__ sr1_g,
        const float* __restrict__ sr1_b, const float* __restrict__ sr1_m,
        const float* __restrict__ sr1_v, const float* __restrict__ sr2_w,
        const float* __restrict__ sr2_g, const float* __restrict__ sr2_b,
        const float* __restrict__ sr2_m, const float* __restrict__ sr2_v,
        const float* __restrict__ local_w, const float* __restrict__ local_b,
        const float* __restrict__ q_w, const float* __restrict__ q_b,
        const float* __restrict__ kv_w, const float* __restrict__ kv_b,
        float* __restrict__ kv2,
        unsigned short* __restrict__ wkq_sw, unsigned short* __restrict__ wv_sw,
        float* __restrict__ kwb, float* __restrict__ wb, float* __restrict__ qkb) {
    int tid = threadIdx.x;
    __shared__ union {
        struct { float xim[H_ * W_]; float kvt[HK_][HK_ + 1]; } sr;
        float wq[64][16];
    } U;

    if (blockIdx.x >= (unsigned)(B_ * C_)) {
        // ---- wprep path ----
        int bx = blockIdx.x - B_ * C_;      // 0..15
        int h  = bx >> 3, cg = bx & 7;
        for (int idx = tid; idx < 64 * 16; idx += 256)
            U.wq[idx >> 4][idx & 15] =
                q_w[(size_t)(h * 64 + (idx >> 4)) * 128 + cg * 16 + (idx & 15)];
        __syncthreads();
        {
            int cl = tid >> 4;
            int c  = cg * 16 + cl;
            int cp0 = (tid & 15) * 8;
            float acc[8];
#pragma unroll
            for (int i = 0; i < 8; ++i) acc[i] = 0.f;
            for (int e = 0; e < 64; ++e) {
                float wqv = U.wq[e][cl];
                const float* wkrow = kv_w + (size_t)(h * 64 + e) * 128 + cp0;
#pragma unroll
                for (int i = 0; i < 8; ++i) acc[i] += wqv * wkrow[i];
            }
            char* base = (char*)wkq_sw + (size_t)h * 32768 + (size_t)c * 256;
            ushort4 u0, u1;
            u0.x = f2b(acc[0] * 0.125f); u0.y = f2b(acc[1] * 0.125f);
            u0.z = f2b(acc[2] * 0.125f); u0.w = f2b(acc[3] * 0.125f);
            u1.x = f2b(acc[4] * 0.125f); u1.y = f2b(acc[5] * 0.125f);
            u1.z = f2b(acc[6] * 0.125f); u1.w = f2b(acc[7] * 0.125f);
            int sw = (c & 7) << 4;
            *(ushort4*)(base + ((cp0 * 2) ^ sw)) = u0;
            *(ushort4*)(base + ((cp0 * 2 + 8) ^ sw)) = u1;
        }
        if (tid < 16) {
            int cl = tid, c = cg * 16 + cl;
            float s = 0.f;
            for (int e = 0; e < 64; ++e) s += kv_b[h * 64 + e] * U.wq[e][cl];
            kwb[h * 128 + c] = s * 0.125f;
        }
        if (cg == 0) {
            if (tid < 128) {
                float s = 0.f;
                for (int e = 0; e < 64; ++e)
                    s += q_b[h * 64 + e] * kv_w[(size_t)(h * 64 + e) * 128 + tid];
                wb[h * 128 + tid] = s * 0.125f;
            }
            if (tid == 0) {
                float s = 0.f;
                for (int e = 0; e < 64; ++e) s += q_b[h * 64 + e] * kv_b[h * 64 + e];
                qkb[h] = s * 0.125f;
            }
        }
        if (cg == 1) {
            for (int idx = tid; idx < 64 * 128; idx += 256) {
                int e = idx >> 7, cp = idx & 127;
                unsigned short val = f2b(kv_w[(size_t)(128 + h * 64 + e) * 128 + cp]);
                *(unsigned short*)((char*)wv_sw + (size_t)h * 16384 + (size_t)e * 256 +
                                   (((cp * 2) ^ ((e & 7) << 4)))) = val;
            }
        }
        return;
    }

    // ---- srlocal path ----
    int bc = blockIdx.x;
    int c  = bc & (C_ - 1);
    const float* xp = x + (size_t)bc * (H_ * W_);
    for (int idx = tid; idx < (H_ * W_) / 4; idx += 256)
        ((float4*)U.sr.xim)[idx] = ((const float4*)xp)[idx];
    __syncthreads();

    int p = tid;
    int oy = p / HK_, ox = p % HK_;
    if (p < NK_) {
        float s = 0.f;
#pragma unroll
        for (int ky = 0; ky < 4; ++ky) {
            int iy = oy * 4 - 2 + ky;
            if (iy < 0 || iy >= H_) continue;
#pragma unroll
            for (int kx = 0; kx < 4; ++kx) {
                int ix = ox * 4 - 2 + kx;
                if (ix < 0 || ix >= W_) continue;
                s += U.sr.xim[iy * W_ + ix] * sr1_w[c * 16 + ky * 4 + kx];
            }
        }
        float inv1 = sr1_g[c] * rsqrtf(sr1_v[c] + 1e-5f);
        s = (s - sr1_m[c]) * inv1 + sr1_b[c];
        s = fmaxf(s, 0.f);
        s *= sr2_w[c];
        float inv2 = sr2_g[c] * rsqrtf(sr2_v[c] + 1e-5f);
        s = (s - sr2_m[c]) * inv2 + sr2_b[c];
        U.sr.kvt[oy][ox] = s;
    }
    __syncthreads();
    if (p < NK_) {
        float v = U.sr.kvt[oy][ox] + local_b[c];
#pragma unroll
        for (int dy = -1; dy <= 1; ++dy) {
            int yy = oy + dy;
            if (yy < 0 || yy >= HK_) continue;
#pragma unroll
            for (int dx = -1; dx <= 1; ++dx) {
                int xx = ox + dx;
                if (xx < 0 || xx >= HK_) continue;
                v += U.sr.kvt[yy][xx] * local_w[c * 9 + (dy + 1) * 3 + (dx + 1)];
            }
        }
        kv2[(size_t)bc * NK_ + p] = v;
    }
}

// ---------------- Kernel 2: kv projection via folded weights, MFMA ----------------
// kw:     [bh][256 rows m][256B c], bf16 swizzled
// bias_s: [bh][256] f32, -1e30 for m>=225
// vbuf:   [bh][64 rows e][512B m], bf16 swizzled (512B rows: 128B-group swizzle bijective)
#define L2B(r, cb) ((r) * 256 + ((cb) ^ (((r) & 7) << 4)))
__global__ __launch_bounds__(256, 2) void kvw_kernel(
        const float* __restrict__ kv2,
        const float* __restrict__ kv_b,
        const unsigned short* __restrict__ wkq_sw,
        const unsigned short* __restrict__ wv_sw,
        const float* __restrict__ kwb,
        const float* __restrict__ wb,
        const float* __restrict__ qkb,
        unsigned short* __restrict__ kw,
        float* __restrict__ bias_s,
        unsigned short* __restrict__ vbuf) {
    int b = blockIdx.x, h = blockIdx.y, mh = blockIdx.z;
    int bh = b * 2 + h;
    int m0 = mh * 64;
    int tid = threadIdx.x;
    int lo = tid & 15, hi = (tid >> 4) & 3, wid = tid >> 6;

    __shared__ char K2[16384];
    __shared__ char WQ[32768];
    __shared__ char WV[16384];

    {
        const char* srcQ = (const char*)wkq_sw + (size_t)h * 32768 + tid * 16;
        char* dstQ = WQ + wid * 1024;
#pragma unroll
        for (int i = 0; i < 8; ++i) gll16(srcQ + i * 4096, dstQ + i * 4096);
        const char* srcV = (const char*)wv_sw + (size_t)h * 16384 + tid * 16;
        char* dstV = WV + wid * 1024;
#pragma unroll
        for (int i = 0; i < 4; ++i) gll16(srcV + i * 4096, dstV + i * 4096);
    }
    {
        int j = tid & 63;
        int mg = m0 + j;
        bool val = (mg < NK_);
#pragma unroll
        for (int it = 0; it < 8; ++it) {
            int c0 = (tid >> 6) * 4 + it * 16;
            ushort4 u;
            if (val) {
                const float* kp = kv2 + ((size_t)b * 128 + c0) * NK_ + mg;
                u.x = f2b(kp[0]);
                u.y = f2b(kp[NK_]);
                u.z = f2b(kp[2 * NK_]);
                u.w = f2b(kp[3 * NK_]);
            } else { u.x = 0; u.y = 0; u.z = 0; u.w = 0; }
            *(ushort4*)(K2 + L2B(j, c0 * 2)) = u;
        }
    }
    __syncthreads();

    bf16x8 aq[4];
#pragma unroll
    for (int ks = 0; ks < 4; ++ks)
        aq[ks] = *(const bf16x8*)(K2 + L2B(wid * 16 + lo, ks * 64 + hi * 16));

    char* kwB = (char*)kw + (size_t)bh * 65536;
#pragma unroll
    for (int ct = 0; ct < 8; ++ct) {
        f32x4 acc = {0.f, 0.f, 0.f, 0.f};
#pragma unroll
        for (int ks = 0; ks < 4; ++ks) {
            bf16x8 bq = *(const bf16x8*)(WQ + L2B(ct * 16 + lo, ks * 64 + hi * 16));
            acc = __builtin_amdgcn_mfma_f32_16x16x32_bf16(aq[ks], bq, acc, 0, 0, 0);
        }
        int c = ct * 16 + lo;
        float kb = kwb[h * 128 + c];
#pragma unroll
        for (int r = 0; r < 4; ++r) {
            int mg = m0 + wid * 16 + hi * 4 + r;
            *(unsigned short*)(kwB + (size_t)mg * 256 + (((c * 2) ^ ((mg & 7) << 4)))) =
                f2b(acc[r] + kb);
        }
    }

    char* vB = (char*)vbuf + (size_t)bh * 32768;
#pragma unroll
    for (int et = 0; et < 4; ++et) {
        f32x4 acc = {0.f, 0.f, 0.f, 0.f};
#pragma unroll
        for (int ks = 0; ks < 4; ++ks) {
            bf16x8 bv = *(const bf16x8*)(WV + L2B(et * 16 + lo, ks * 64 + hi * 16));
            acc = __builtin_amdgcn_mfma_f32_16x16x32_bf16(aq[ks], bv, acc, 0, 0, 0);
        }
        int e = et * 16 + lo;
        float vb = kv_b[128 + h * 64 + e];
#pragma unroll
        for (int r = 0; r < 4; ++r) {
            int mg = m0 + wid * 16 + hi * 4 + r;
            *(unsigned short*)(vB + (size_t)e * 512 + (((mg * 2) ^ ((e & 7) << 4)))) =
                f2b(acc[r] + vb);
        }
    }

    if (tid < 64) {
        int mg = m0 + tid;
        float s;
        if (mg >= NK_) s = -1e30f;
        else {
            s = qkb[h];
            for (int i = 0; i < 128; ++i) {
                int cp = (i + (tid & 7) * 16) & 127;
                s += b2f(*(const unsigned short*)(K2 + L2B(tid, cp * 2))) * wb[h * 128 + cp];
            }
        }
        bias_s[(size_t)bh * 256 + mg] = s;
    }
}

// ---------------- Kernel 3: fused attention, swapped-S, no P-LDS, 3 blocks/CU ----------------
#define XTB(j, c) ((j) * 256 + (((c) * 2) ^ (((j) & 15) << 4)))
#define KWB(rl, cb) ((rl) * 256 + ((cb) ^ (((rl) & 7) << 4)))
#define CVB(e, cb)  ((e) * 512 + ((cb) ^ (((e) & 7) << 4)))

__global__ __launch_bounds__(256, 3) void attn_kernel(
        const float* __restrict__ x,
        const unsigned short* __restrict__ kw,
        const float* __restrict__ bias_s,
        const unsigned short* __restrict__ vbuf,
        float* __restrict__ out) {
    // XCD-pinned decode: all 49 j-tiles of a given bh land on one XCD
    int flat = blockIdx.x;              // 0..3135
    int xcd  = flat & 7;
    int idx  = flat >> 3;               // 0..391
    int g    = idx / 49;                // 0..7
    int jt   = idx % 49;
    int bh   = g * 8 + xcd;
    int bb   = bh >> 1;
    int h    = bh & 1;
    int n0   = jt * 64;
    int tid = threadIdx.x;
    int lo  = tid & 15;
    int hi  = (tid >> 4) & 3;
    int wid = tid >> 6;
    int jw  = wid * 16;

    __shared__ char LA[16384];       // xt (prologue) then Bt[2][8192] (S loop)
    __shared__ char LC[32768];       // V: 64 rows x 512B, swizzled
    __shared__ float LBIAS[256];     // 1 KB
    // total 50176 B = 49 KB -> 3 blocks/CU

    const char* kwG = (const char*)kw + (size_t)bh * 65536;
    const char* vG  = (const char*)vbuf + (size_t)bh * 32768;

    // ---- prologue: issue Cv + bias DMA first (oldest in vmcnt ledger) ----
    {
#pragma unroll
        for (int i = 0; i < 8; ++i)
            gll16(vG + i * 4096 + tid * 16, LC + i * 4096 + wid * 1024);
        if (wid == 0)
            gll16((const char*)(bias_s + (size_t)bh * 256) + tid * 16, (char*)LBIAS);
    }
    // xt stage: coalesced f32 loads, reg transpose -> bf16, swizzled LDS
#pragma unroll
    for (int it = 0; it < 8; ++it) {
        int j  = tid & 63;
        int c0 = (tid >> 6) * 4 + it * 16;
        const float* xp = x + ((size_t)bb * 128 + c0) * N_ + n0 + j;
        ushort4 u;
        u.x = f2b(xp[0]);
        u.y = f2b(xp[(size_t)N_]);
        u.z = f2b(xp[2 * (size_t)N_]);
        u.w = f2b(xp[3 * (size_t)N_]);
        *(ushort4*)(LA + XTB(j, c0)) = u;
    }
    asm volatile("s_waitcnt lgkmcnt(0)" ::: "memory");
    __builtin_amdgcn_s_barrier();

    // A/B xt fragments for this wave's 16 j columns
    bf16x8 aq[4];
#pragma unroll
    for (int ks = 0; ks < 4; ++ks)
        aq[ks] = *(const bf16x8*)(LA + XTB(jw + lo, ks * 32 + hi * 8));
    asm volatile("s_waitcnt lgkmcnt(0)" ::: "memory");
    __builtin_amdgcn_s_barrier();          // xt region now free for Bt
    __builtin_amdgcn_sched_barrier(0);

    // issue kw0, kw1 into LA (overlaying dead xt)
    {
        const char* s0 = kwG + tid * 16;
        char* d0 = LA + wid * 1024;
        gll16(s0, d0); gll16(s0 + 4096, d0 + 4096);
        const char* s1 = kwG + 8192 + tid * 16;
        char* d1 = LA + 8192 + wid * 1024;
        gll16(s1, d1); gll16(s1 + 4096, d1 + 4096);
    }
    // wait kw0 (allows kw1's 2 in flight; forces older Cv+bias complete too)
    asm volatile("s_waitcnt vmcnt(2)" ::: "memory");
    __builtin_amdgcn_s_barrier();
    __builtin_amdgcn_sched_barrier(0);

    // ---- S^T loop: s[mt] holds S[m=mt*16+hi*4+r][j=jw+lo] (swapped operands) ----
    f32x4 s[15];
#pragma unroll
    for (int t = 0; t < 8; ++t) {
        char* Bt = LA + (t & 1) * 8192;
#pragma unroll
        for (int ml = 0; ml < 2; ++ml) {
            int mt = t * 2 + ml;
            if (mt >= 15) continue;
            f32x4 acc = {0.f, 0.f, 0.f, 0.f};
#pragma unroll
            for (int ks = 0; ks < 4; ++ks) {
                bf16x8 bk = *(const bf16x8*)(Bt + KWB(ml * 16 + lo, ks * 64 + hi * 16));
                acc = __builtin_amdgcn_mfma_f32_16x16x32_bf16(bk, aq[ks], acc, 0, 0, 0);
            }
            s[mt] = acc;
        }
        if (t < 6) {
            __builtin_amdgcn_s_barrier();              // all waves done reading Bt[t&1]
            const char* sn = kwG + (t + 2) * 8192 + tid * 16;
            char* dn = LA + (t & 1) * 8192 + wid * 1024;
            gll16(sn, dn); gll16(sn + 4096, dn + 4096);
        }
        if (t < 7) {
            if (t < 6) asm volatile("s_waitcnt vmcnt(2)" ::: "memory");
            else       asm volatile("s_waitcnt vmcnt(0)" ::: "memory");
            __builtin_amdgcn_s_barrier();
            __builtin_amdgcn_sched_barrier(0);
        }
    }

    // ---- bias add (LDS broadcast reads) ----
#pragma unroll
    for (int mt = 0; mt < 15; ++mt) {
        f32x4 bv = *(const f32x4*)&LBIAS[mt * 16 + hi * 4];
#pragma unroll
        for (int r = 0; r < 4; ++r) s[mt][r] += bv[r];
    }

    // ---- softmax over m for fixed j=jw+lo: in-register + shfl over hi groups ----
    float mxv = s[0][0];
#pragma unroll
    for (int mt = 0; mt < 15; ++mt) {
#pragma unroll
        for (int r = 0; r < 4; ++r) mxv = fmaxf(mxv, s[mt][r]);
    }
    mxv = fmaxf(mxv, __shfl_xor(mxv, 16));
    mxv = fmaxf(mxv, __shfl_xor(mxv, 32));
    float smv = 0.f;
#pragma unroll
    for (int mt = 0; mt < 15; ++mt) {
#pragma unroll
        for (int r = 0; r < 4; ++r) {
            float pe = __expf(s[mt][r] - mxv);
            s[mt][r] = pe;
            smv += pe;
        }
    }
    smv += __shfl_xor(smv, 16);
    smv += __shfl_xor(smv, 32);
    float rinv = 1.f / smv;

    // ---- in-register transpose: build PV B-fragments bp[ks] ----
    // bp[ks] lane(lo,hi) elem idx = P[m=ks*32+hi*8+idx][j=jw+lo]
    bf16x8 bp[8];
    int sA = lo + (hi & 1) * 32;
    int sB = sA + 16;
    bool lowm = (hi < 2);
#pragma unroll
    for (int ks = 0; ks < 8; ++ks) {
        int t0 = 2 * ks, t1 = 2 * ks + 1;
        unsigned int a0 = pkbf(s[t0][0], s[t0][1]);
        unsigned int a1 = pkbf(s[t0][2], s[t0][3]);
        unsigned int r0A = (unsigned int)__shfl((int)a0, sA);
        unsigned int r1A = (unsigned int)__shfl((int)a1, sA);
        unsigned int r0B = (unsigned int)__shfl((int)a0, sB);
        unsigned int r1B = (unsigned int)__shfl((int)a1, sB);
        unsigned int dw0, dw1, dw2, dw3;
        if (ks < 7) {
            unsigned int b0 = pkbf(s[t1][0], s[t1][1]);
            unsigned int b1 = pkbf(s[t1][2], s[t1][3]);
            unsigned int q0A = (unsigned int)__shfl((int)b0, sA);
            unsigned int q1A = (unsigned int)__shfl((int)b1, sA);
            unsigned int q0B = (unsigned int)__shfl((int)b0, sB);
            unsigned int q1B = (unsigned int)__shfl((int)b1, sB);
            dw0 = lowm ? r0A : q0A;
            dw1 = lowm ? r1A : q1A;
            dw2 = lowm ? r0B : q0B;
            dw3 = lowm ? r1B : q1B;
        } else {
            dw0 = lowm ? r0A : 0u;
            dw1 = lowm ? r1A : 0u;
            dw2 = lowm ? r0B : 0u;
            dw3 = lowm ? r1B : 0u;
        }
        uint4 d4 = {dw0, dw1, dw2, dw3};
        bp[ks] = *(bf16x8*)&d4;
    }

    // ---- PV: O[e][j] = V^T[e][m] . P[m][j]; A-frags from LC, deferred rinv ----
#pragma unroll
    for (int et = 0; et < 4; ++et) {
        f32x4 acc = {0.f, 0.f, 0.f, 0.f};
#pragma unroll
        for (int ks = 0; ks < 8; ++ks) {
            bf16x8 av = *(const bf16x8*)(LC + CVB(et * 16 + lo, ks * 64 + hi * 16));
            acc = __builtin_amdgcn_mfma_f32_16x16x32_bf16(av, bp[ks], acc, 0, 0, 0);
        }
        int e = et * 16 + hi * 4;
#pragma unroll
        for (int r = 0; r < 4; ++r)
            out[((size_t)bb * 128 + h * 64 + e + r) * N_ + n0 + jw + lo] = acc[r] * rinv;
    }
}

extern "C" void kernel_launch(void* const* d_in, const int* in_sizes, int n_in,
                              void* d_out, int out_size, void* d_ws, size_t ws_size,
                              hipStream_t stream) {
    const float* x       = (const float*)d_in[0];
    const float* q_w     = (const float*)d_in[1];
    const float* q_b     = (const float*)d_in[2];
    const float* kv_w    = (const float*)d_in[3];
    const float* kv_b    = (const float*)d_in[4];
    const float* sr1_w   = (const float*)d_in[5];
    const float* sr1_g   = (const float*)d_in[6];
    const float* sr1_b   = (const float*)d_in[7];
    const float* sr1_m   = (const float*)d_in[8];
    const float* sr1_v   = (const float*)d_in[9];
    const float* sr2_w   = (const float*)d_in[10];
    const float* sr2_g   = (const float*)d_in[11];
    const float* sr2_b   = (const float*)d_in[12];
    const float* sr2_m   = (const float*)d_in[13];
    const float* sr2_v   = (const float*)d_in[14];
    const float* local_w = (const float*)d_in[15];
    const float* local_b = (const float*)d_in[16];

    char* ws = (char*)d_ws;
    float* kv2              = (float*)(ws + 0);                 // 3,686,400 B
    unsigned short* wkq_sw  = (unsigned short*)(ws + 3686400);  //    65,536 B
    unsigned short* wv_sw   = (unsigned short*)(ws + 3751936);  //    32,768 B
    unsigned short* kw      = (unsigned short*)(ws + 3784704);  // 4,194,304 B
    unsigned short* vbuf    = (unsigned short*)(ws + 7979008);  // 2,097,152 B
    float* bias_s           = (float*)(ws + 10076160);          //    65,536 B
    float* kwb              = (float*)(ws + 10141696);          //     1,024 B
    float* wb               = (float*)(ws + 10142720);          //     1,024 B
    float* qkb              = (float*)(ws + 10143744);          //         8 B

    prep_kernel<<<B_ * C_ + 16, 256, 0, stream>>>(
        x, sr1_w, sr1_g, sr1_b, sr1_m, sr1_v,
        sr2_w, sr2_g, sr2_b, sr2_m, sr2_v, local_w, local_b,
        q_w, q_b, kv_w, kv_b,
        kv2, wkq_sw, wv_sw, kwb, wb, qkb);
    kvw_kernel<<<dim3(B_, 2, 4), 256, 0, stream>>>(
        kv2, kv_b, wkq_sw, wv_sw, kwb, wb, qkb, kw, bias_s, vbuf);
    attn_kernel<<<3136, 256, 0, stream>>>(
        x, kw, bias_s, vbuf, (float*)d_out);
}

// Round 13
// 86.280 us; speedup vs baseline: 1.1982x; 1.0372x over previous
//
#include <hip/hip_runtime.h>
#include <hip/hip_bf16.h>

#define B_    32
#define C_    128
#define H_    56
#define W_    56
#define N_    3136
#define HK_   15
#define NK_   225
#define D_    64
#define SCL_  0.1803368801111731f   // 0.125 * log2(e): exp2-domain softmax

typedef __attribute__((ext_vector_type(8))) short bf16x8;
typedef __attribute__((ext_vector_type(4))) float f32x4;

__device__ __forceinline__ float b2f(unsigned short u) {
    union { float f; unsigned int i; } x;
    x.i = ((unsigned int)u) << 16;
    return x.f;
}
__device__ __forceinline__ unsigned short f2b(float f) {
    __hip_bfloat16 h = __float2bfloat16(f);
    return *(unsigned short*)&h;
}
// packed f32x2 -> bf16x2 (HW RNE, 1 inst): low half = a
__device__ __forceinline__ unsigned int cvtpk(float a, float b) {
    unsigned int r;
    asm("v_cvt_pk_bf16_f32 %0, %1, %2" : "=v"(r) : "v"(a), "v"(b));
    return r;
}
__device__ __forceinline__ float exp2a(float x) {
    float r;
    asm("v_exp_f32 %0, %1" : "=v"(r) : "v"(x));
    return r;
}

// async global -> LDS, 16B/lane; LDS dest wave-uniform base (HW adds lane*16)
__device__ __forceinline__ void gll16(const char* g, char* l) {
    __builtin_amdgcn_global_load_lds(
        (const __attribute__((address_space(1))) unsigned int*)g,
        (__attribute__((address_space(3))) unsigned int*)l,
        16, 0, 0);
}

// ---------------- Kernel 1: fused sr + local conv, with wprep merged (blocks >= 4096) ----
__global__ __launch_bounds__(256) void prep_kernel(
        const float* __restrict__ x,
        const float* __restrict__ sr1_w, const float* __restrict__ sr1_g,
        const float* __restrict__ sr1_b, const float* __restrict__ sr1_m,
        const float* __restrict__ sr1_v, const float* __restrict__ sr2_w,
        const float* __restrict__ sr2_g, const float* __restrict__ sr2_b,
        const float* __restrict__ sr2_m, const float* __restrict__ sr2_v,
        const float* __restrict__ local_w, const float* __restrict__ local_b,
        const float* __restrict__ q_w, const float* __restrict__ q_b,
        const float* __restrict__ kv_w, const float* __restrict__ kv_b,
        float* __restrict__ kv2,
        unsigned short* __restrict__ wkq_sw, unsigned short* __restrict__ wv_sw,
        float* __restrict__ kwb, float* __restrict__ wb, float* __restrict__ qkb) {
    int tid = threadIdx.x;
    __shared__ union {
        struct { float xim[H_ * W_]; float kvt[HK_][HK_ + 1]; } sr;
        float wq[64][16];
    } U;

    if (blockIdx.x >= (unsigned)(B_ * C_)) {
        // ---- wprep path (all S-side factors scaled by SCL_ = 0.125*log2e) ----
        int bx = blockIdx.x - B_ * C_;      // 0..15
        int h  = bx >> 3, cg = bx & 7;
        for (int idx = tid; idx < 64 * 16; idx += 256)
            U.wq[idx >> 4][idx & 15] =
                q_w[(size_t)(h * 64 + (idx >> 4)) * 128 + cg * 16 + (idx & 15)];
        __syncthreads();
        {
            int cl = tid >> 4;
            int c  = cg * 16 + cl;
            int cp0 = (tid & 15) * 8;
            float acc[8];
#pragma unroll
            for (int i = 0; i < 8; ++i) acc[i] = 0.f;
            for (int e = 0; e < 64; ++e) {
                float wqv = U.wq[e][cl];
                const float* wkrow = kv_w + (size_t)(h * 64 + e) * 128 + cp0;
#pragma unroll
                for (int i = 0; i < 8; ++i) acc[i] += wqv * wkrow[i];
            }
            char* base = (char*)wkq_sw + (size_t)h * 32768 + (size_t)c * 256;
            ushort4 u0, u1;
            u0.x = f2b(acc[0] * SCL_); u0.y = f2b(acc[1] * SCL_);
            u0.z = f2b(acc[2] * SCL_); u0.w = f2b(acc[3] * SCL_);
            u1.x = f2b(acc[4] * SCL_); u1.y = f2b(acc[5] * SCL_);
            u1.z = f2b(acc[6] * SCL_); u1.w = f2b(acc[7] * SCL_);
            int sw = (c & 7) << 4;
            *(ushort4*)(base + ((cp0 * 2) ^ sw)) = u0;
            *(ushort4*)(base + ((cp0 * 2 + 8) ^ sw)) = u1;
        }
        if (tid < 16) {
            int cl = tid, c = cg * 16 + cl;
            float s = 0.f;
            for (int e = 0; e < 64; ++e) s += kv_b[h * 64 + e] * U.wq[e][cl];
            kwb[h * 128 + c] = s * SCL_;
        }
        if (cg == 0) {
            if (tid < 128) {
                float s = 0.f;
                for (int e = 0; e < 64; ++e)
                    s += q_b[h * 64 + e] * kv_w[(size_t)(h * 64 + e) * 128 + tid];
                wb[h * 128 + tid] = s * SCL_;
            }
            if (tid == 0) {
                float s = 0.f;
                for (int e = 0; e < 64; ++e) s += q_b[h * 64 + e] * kv_b[h * 64 + e];
                qkb[h] = s * SCL_;
            }
        }
        if (cg == 1) {
            for (int idx = tid; idx < 64 * 128; idx += 256) {
                int e = idx >> 7, cp = idx & 127;
                unsigned short val = f2b(kv_w[(size_t)(128 + h * 64 + e) * 128 + cp]);
                *(unsigned short*)((char*)wv_sw + (size_t)h * 16384 + (size_t)e * 256 +
                                   (((cp * 2) ^ ((e & 7) << 4)))) = val;
            }
        }
        return;
    }

    // ---- srlocal path ----
    int bc = blockIdx.x;
    int c  = bc & (C_ - 1);
    const float* xp = x + (size_t)bc * (H_ * W_);
    for (int idx = tid; idx < (H_ * W_) / 4; idx += 256)
        ((float4*)U.sr.xim)[idx] = ((const float4*)xp)[idx];
    __syncthreads();

    int p = tid;
    int oy = p / HK_, ox = p % HK_;
    if (p < NK_) {
        float s = 0.f;
#pragma unroll
        for (int ky = 0; ky < 4; ++ky) {
            int iy = oy * 4 - 2 + ky;
            if (iy < 0 || iy >= H_) continue;
#pragma unroll
            for (int kx = 0; kx < 4; ++kx) {
                int ix = ox * 4 - 2 + kx;
                if (ix < 0 || ix >= W_) continue;
                s += U.sr.xim[iy * W_ + ix] * sr1_w[c * 16 + ky * 4 + kx];
            }
        }
        float inv1 = sr1_g[c] * rsqrtf(sr1_v[c] + 1e-5f);
        s = (s - sr1_m[c]) * inv1 + sr1_b[c];
        s = fmaxf(s, 0.f);
        s *= sr2_w[c];
        float inv2 = sr2_g[c] * rsqrtf(sr2_v[c] + 1e-5f);
        s = (s - sr2_m[c]) * inv2 + sr2_b[c];
        U.sr.kvt[oy][ox] = s;
    }
    __syncthreads();
    if (p < NK_) {
        float v = U.sr.kvt[oy][ox] + local_b[c];
#pragma unroll
        for (int dy = -1; dy <= 1; ++dy) {
            int yy = oy + dy;
            if (yy < 0 || yy >= HK_) continue;
#pragma unroll
            for (int dx = -1; dx <= 1; ++dx) {
                int xx = ox + dx;
                if (xx < 0 || xx >= HK_) continue;
                v += U.sr.kvt[yy][xx] * local_w[c * 9 + (dy + 1) * 3 + (dx + 1)];
            }
        }
        kv2[(size_t)bc * NK_ + p] = v;
    }
}

// ---------------- Kernel 2: kv projection via folded weights, MFMA ----------------
// kw:     [bh][256 rows m][256B c], bf16 swizzled (SCL_-scaled)
// bias_s: [bh][256] f32 (SCL_-scaled), -1e30 for m>=225
// vbuf:   [bh][64 rows e][512B m], bf16 swizzled
#define L2B(r, cb) ((r) * 256 + ((cb) ^ (((r) & 7) << 4)))
__global__ __launch_bounds__(256, 2) void kvw_kernel(
        const float* __restrict__ kv2,
        const float* __restrict__ kv_b,
        const unsigned short* __restrict__ wkq_sw,
        const unsigned short* __restrict__ wv_sw,
        const float* __restrict__ kwb,
        const float* __restrict__ wb,
        const float* __restrict__ qkb,
        unsigned short* __restrict__ kw,
        float* __restrict__ bias_s,
        unsigned short* __restrict__ vbuf) {
    int b = blockIdx.x, h = blockIdx.y, mh = blockIdx.z;
    int bh = b * 2 + h;
    int m0 = mh * 64;
    int tid = threadIdx.x;
    int lo = tid & 15, hi = (tid >> 4) & 3, wid = tid >> 6;

    __shared__ char K2[16384];
    __shared__ char WQ[32768];
    __shared__ char WV[16384];

    {
        const char* srcQ = (const char*)wkq_sw + (size_t)h * 32768 + tid * 16;
        char* dstQ = WQ + wid * 1024;
#pragma unroll
        for (int i = 0; i < 8; ++i) gll16(srcQ + i * 4096, dstQ + i * 4096);
        const char* srcV = (const char*)wv_sw + (size_t)h * 16384 + tid * 16;
        char* dstV = WV + wid * 1024;
#pragma unroll
        for (int i = 0; i < 4; ++i) gll16(srcV + i * 4096, dstV + i * 4096);
    }
    {
        int j = tid & 63;
        int mg = m0 + j;
        bool val = (mg < NK_);
#pragma unroll
        for (int it = 0; it < 8; ++it) {
            int c0 = (tid >> 6) * 4 + it * 16;
            ushort4 u;
            if (val) {
                const float* kp = kv2 + ((size_t)b * 128 + c0) * NK_ + mg;
                u.x = f2b(kp[0]);
                u.y = f2b(kp[NK_]);
                u.z = f2b(kp[2 * NK_]);
                u.w = f2b(kp[3 * NK_]);
            } else { u.x = 0; u.y = 0; u.z = 0; u.w = 0; }
            *(ushort4*)(K2 + L2B(j, c0 * 2)) = u;
        }
    }
    __syncthreads();

    bf16x8 aq[4];
#pragma unroll
    for (int ks = 0; ks < 4; ++ks)
        aq[ks] = *(const bf16x8*)(K2 + L2B(wid * 16 + lo, ks * 64 + hi * 16));

    char* kwB = (char*)kw + (size_t)bh * 65536;
#pragma unroll
    for (int ct = 0; ct < 8; ++ct) {
        f32x4 acc = {0.f, 0.f, 0.f, 0.f};
#pragma unroll
        for (int ks = 0; ks < 4; ++ks) {
            bf16x8 bq = *(const bf16x8*)(WQ + L2B(ct * 16 + lo, ks * 64 + hi * 16));
            acc = __builtin_amdgcn_mfma_f32_16x16x32_bf16(aq[ks], bq, acc, 0, 0, 0);
        }
        int c = ct * 16 + lo;
        float kb = kwb[h * 128 + c];
#pragma unroll
        for (int r = 0; r < 4; ++r) {
            int mg = m0 + wid * 16 + hi * 4 + r;
            *(unsigned short*)(kwB + (size_t)mg * 256 + (((c * 2) ^ ((mg & 7) << 4)))) =
                f2b(acc[r] + kb);
        }
    }

    char* vB = (char*)vbuf + (size_t)bh * 32768;
#pragma unroll
    for (int et = 0; et < 4; ++et) {
        f32x4 acc = {0.f, 0.f, 0.f, 0.f};
#pragma unroll
        for (int ks = 0; ks < 4; ++ks) {
            bf16x8 bv = *(const bf16x8*)(WV + L2B(et * 16 + lo, ks * 64 + hi * 16));
            acc = __builtin_amdgcn_mfma_f32_16x16x32_bf16(aq[ks], bv, acc, 0, 0, 0);
        }
        int e = et * 16 + lo;
        float vb = kv_b[128 + h * 64 + e];
#pragma unroll
        for (int r = 0; r < 4; ++r) {
            int mg = m0 + wid * 16 + hi * 4 + r;
            *(unsigned short*)(vB + (size_t)e * 512 + (((mg * 2) ^ ((e & 7) << 4)))) =
                f2b(acc[r] + vb);
        }
    }

    if (tid < 64) {
        int mg = m0 + tid;
        float s;
        if (mg >= NK_) s = -1e30f;
        else {
            s = qkb[h];
            for (int i = 0; i < 128; ++i) {
                int cp = (i + (tid & 7) * 16) & 127;
                s += b2f(*(const unsigned short*)(K2 + L2B(tid, cp * 2))) * wb[h * 128 + cp];
            }
        }
        bias_s[(size_t)bh * 256 + mg] = s;
    }
}

// ---------------- Kernel 3: fused attention, swapped-S, x-direct-to-reg, 3 blocks/CU ----
#define KWB(rl, cb) ((rl) * 256 + ((cb) ^ (((rl) & 7) << 4)))
#define CVB(e, cb)  ((e) * 512 + ((cb) ^ (((e) & 7) << 4)))

__global__ __launch_bounds__(256, 3) void attn_kernel(
        const float* __restrict__ x,
        const unsigned short* __restrict__ kw,
        const float* __restrict__ bias_s,
        const unsigned short* __restrict__ vbuf,
        float* __restrict__ out) {
    // XCD-pinned decode: all 49 j-tiles of a given bh land on one XCD
    int flat = blockIdx.x;              // 0..3135
    int xcd  = flat & 7;
    int idx  = flat >> 3;               // 0..391
    int g    = idx / 49;                // 0..7
    int jt   = idx % 49;
    int bh   = g * 8 + xcd;
    int bb   = bh >> 1;
    int h    = bh & 1;
    int n0   = jt * 64;
    int tid = threadIdx.x;
    int lo  = tid & 15;
    int hi  = (tid >> 4) & 3;
    int wid = tid >> 6;
    int jw  = wid * 16;

    __shared__ char LA[16384];       // kw tile double-buffer: 2 x 32 rows x 256B
    __shared__ char LC[32768];       // V: 64 rows x 512B, swizzled
    __shared__ float LBIAS[256];     // 1 KB       (total 49 KB -> 3 blocks/CU)

    const char* kwG = (const char*)kw + (size_t)bh * 65536;
    const char* vG  = (const char*)vbuf + (size_t)bh * 32768;

    // ---- x fragment loads straight to registers (oldest in vmcnt ledger) ----
    const float* xb = x + ((size_t)bb * 128) * N_ + n0 + jw + lo;
    float xf[4][8];
#pragma unroll
    for (int ks = 0; ks < 4; ++ks) {
#pragma unroll
        for (int i = 0; i < 8; ++i)
            xf[ks][i] = xb[(size_t)(ks * 32 + hi * 8 + i) * N_];
    }
    __builtin_amdgcn_sched_barrier(0);   // keep x loads ahead of the DMA ledger

    // ---- DMA ledger: bias(1), kw0(2), kw1(2), Cv(8) ----
    {
        if (wid == 0)
            gll16((const char*)(bias_s + (size_t)bh * 256) + tid * 16, (char*)LBIAS);
        const char* s0 = kwG + tid * 16;
        char* d0 = LA + wid * 1024;
        gll16(s0, d0); gll16(s0 + 4096, d0 + 4096);
        const char* s1 = kwG + 8192 + tid * 16;
        char* d1 = LA + 8192 + wid * 1024;
        gll16(s1, d1); gll16(s1 + 4096, d1 + 4096);
        const char* sc = vG + tid * 16;
        char* dc = LC + wid * 1024;
#pragma unroll
        for (int i = 0; i < 8; ++i) gll16(sc + i * 4096, dc + i * 4096);
    }

    // pack aq fragments (compiler inserts counted vmcnt for xf; DMAs stay in flight)
    bf16x8 aq[4];
#pragma unroll
    for (int ks = 0; ks < 4; ++ks) {
        uint4 u;
        u.x = cvtpk(xf[ks][0], xf[ks][1]);
        u.y = cvtpk(xf[ks][2], xf[ks][3]);
        u.z = cvtpk(xf[ks][4], xf[ks][5]);
        u.w = cvtpk(xf[ks][6], xf[ks][7]);
        aq[ks] = *(bf16x8*)&u;
    }

    // bias + kw0 ready (kw1(2) + Cv(8) may stay in flight)
    asm volatile("s_waitcnt vmcnt(10)" ::: "memory");
    __builtin_amdgcn_s_barrier();
    __builtin_amdgcn_sched_barrier(0);

    // ---- S^T loop: s[mt] = S[m=mt*16+hi*4+r][j=jw+lo]; bias as MFMA C-init ----
    f32x4 s[15];
#pragma unroll
    for (int t = 0; t < 8; ++t) {
        char* Bt = LA + (t & 1) * 8192;
#pragma unroll
        for (int ml = 0; ml < 2; ++ml) {
            int mt = t * 2 + ml;
            if (mt >= 15) continue;
            f32x4 acc = *(const f32x4*)&LBIAS[mt * 16 + hi * 4];
#pragma unroll
            for (int ks = 0; ks < 4; ++ks) {
                bf16x8 bk = *(const bf16x8*)(Bt + KWB(ml * 16 + lo, ks * 64 + hi * 16));
                acc = __builtin_amdgcn_mfma_f32_16x16x32_bf16(bk, aq[ks], acc, 0, 0, 0);
            }
            s[mt] = acc;
        }
        if (t < 6) {
            __builtin_amdgcn_s_barrier();              // all waves done reading Bt[t&1]
            const char* sn = kwG + (t + 2) * 8192 + tid * 16;
            char* dn = LA + (t & 1) * 8192 + wid * 1024;
            gll16(sn, dn); gll16(sn + 4096, dn + 4096);
        }
        if (t < 7) {
            if (t == 0)      asm volatile("s_waitcnt vmcnt(10)" ::: "memory");
            else if (t < 6)  asm volatile("s_waitcnt vmcnt(2)" ::: "memory");
            else             asm volatile("s_waitcnt vmcnt(0)" ::: "memory");
            __builtin_amdgcn_s_barrier();
            __builtin_amdgcn_sched_barrier(0);
        }
    }

    // ---- softmax over m (exp2 domain; masked rows carry -1e30 bias -> 0) ----
    float mxv = s[0][0];
#pragma unroll
    for (int mt = 0; mt < 15; ++mt) {
#pragma unroll
        for (int r = 0; r < 4; ++r) mxv = fmaxf(mxv, s[mt][r]);
    }
    mxv = fmaxf(mxv, __shfl_xor(mxv, 16));
    mxv = fmaxf(mxv, __shfl_xor(mxv, 32));
    float smv = 0.f;
#pragma unroll
    for (int mt = 0; mt < 15; ++mt) {
#pragma unroll
        for (int r = 0; r < 4; ++r) {
            float pe = exp2a(s[mt][r] - mxv);
            s[mt][r] = pe;
            smv += pe;
        }
    }
    smv += __shfl_xor(smv, 16);
    smv += __shfl_xor(smv, 32);
    float rinv = 1.f / smv;

    // ---- in-register transpose: build PV B-fragments bp[ks] ----
    bf16x8 bp[8];
    int sA = lo + (hi & 1) * 32;
    int sB = sA + 16;
    bool lowm = (hi < 2);
#pragma unroll
    for (int ks = 0; ks < 8; ++ks) {
        int t0 = 2 * ks, t1 = 2 * ks + 1;
        unsigned int a0 = cvtpk(s[t0][0], s[t0][1]);
        unsigned int a1 = cvtpk(s[t0][2], s[t0][3]);
        unsigned int r0A = (unsigned int)__shfl((int)a0, sA);
        unsigned int r1A = (unsigned int)__shfl((int)a1, sA);
        unsigned int r0B = (unsigned int)__shfl((int)a0, sB);
        unsigned int r1B = (unsigned int)__shfl((int)a1, sB);
        unsigned int dw0, dw1, dw2, dw3;
        if (ks < 7) {
            unsigned int b0 = cvtpk(s[t1][0], s[t1][1]);
            unsigned int b1 = cvtpk(s[t1][2], s[t1][3]);
            unsigned int q0A = (unsigned int)__shfl((int)b0, sA);
            unsigned int q1A = (unsigned int)__shfl((int)b1, sA);
            unsigned int q0B = (unsigned int)__shfl((int)b0, sB);
            unsigned int q1B = (unsigned int)__shfl((int)b1, sB);
            dw0 = lowm ? r0A : q0A;
            dw1 = lowm ? r1A : q1A;
            dw2 = lowm ? r0B : q0B;
            dw3 = lowm ? r1B : q1B;
        } else {
            dw0 = lowm ? r0A : 0u;
            dw1 = lowm ? r1A : 0u;
            dw2 = lowm ? r0B : 0u;
            dw3 = lowm ? r1B : 0u;
        }
        uint4 d4 = {dw0, dw1, dw2, dw3};
        bp[ks] = *(bf16x8*)&d4;
    }

    // ---- PV: O[e][j] = V^T[e][m] . P[m][j]; deferred rinv ----
#pragma unroll
    for (int et = 0; et < 4; ++et) {
        f32x4 acc = {0.f, 0.f, 0.f, 0.f};
#pragma unroll
        for (int ks = 0; ks < 8; ++ks) {
            bf16x8 av = *(const bf16x8*)(LC + CVB(et * 16 + lo, ks * 64 + hi * 16));
            acc = __builtin_amdgcn_mfma_f32_16x16x32_bf16(av, bp[ks], acc, 0, 0, 0);
        }
        int e = et * 16 + hi * 4;
#pragma unroll
        for (int r = 0; r < 4; ++r)
            out[((size_t)bb * 128 + h * 64 + e + r) * N_ + n0 + jw + lo] = acc[r] * rinv;
    }
}

extern "C" void kernel_launch(void* const* d_in, const int* in_sizes, int n_in,
                              void* d_out, int out_size, void* d_ws, size_t ws_size,
                              hipStream_t stream) {
    const float* x       = (const float*)d_in[0];
    const float* q_w     = (const float*)d_in[1];
    const float* q_b     = (const float*)d_in[2];
    const float* kv_w    = (const float*)d_in[3];
    const float* kv_b    = (const float*)d_in[4];
    const float* sr1_w   = (const float*)d_in[5];
    const float* sr1_g   = (const float*)d_in[6];
    const float* sr1_b   = (const float*)d_in[7];
    const float* sr1_m   = (const float*)d_in[8];
    const float* sr1_v   = (const float*)d_in[9];
    const float* sr2_w   = (const float*)d_in[10];
    const float* sr2_g   = (const float*)d_in[11];
    const float* sr2_b   = (const float*)d_in[12];
    const float* sr2_m   = (const float*)d_in[13];
    const float* sr2_v   = (const float*)d_in[14];
    const float* local_w = (const float*)d_in[15];
    const float* local_b = (const float*)d_in[16];

    char* ws = (char*)d_ws;
    float* kv2              = (float*)(ws + 0);                 // 3,686,400 B
    unsigned short* wkq_sw  = (unsigned short*)(ws + 3686400);  //    65,536 B
    unsigned short* wv_sw   = (unsigned short*)(ws + 3751936);  //    32,768 B
    unsigned short* kw      = (unsigned short*)(ws + 3784704);  // 4,194,304 B
    unsigned short* vbuf    = (unsigned short*)(ws + 7979008);  // 2,097,152 B
    float* bias_s           = (float*)(ws + 10076160);          //    65,536 B
    float* kwb              = (float*)(ws + 10141696);          //     1,024 B
    float* wb               = (float*)(ws + 10142720);          //     1,024 B
    float* qkb              = (float*)(ws + 10143744);          //         8 B

    prep_kernel<<<B_ * C_ + 16, 256, 0, stream>>>(
        x, sr1_w, sr1_g, sr1_b, sr1_m, sr1_v,
        sr2_w, sr2_g, sr2_b, sr2_m, sr2_v, local_w, local_b,
        q_w, q_b, kv_w, kv_b,
        kv2, wkq_sw, wv_sw, kwb, wb, qkb);
    kvw_kernel<<<dim3(B_, 2, 4), 256, 0, stream>>>(
        kv2, kv_b, wkq_sw, wv_sw, kwb, wb, qkb, kw, bias_s, vbuf);
    attn_kernel<<<3136, 256, 0, stream>>>(
        x, kw, bias_s, vbuf, (float*)d_out);
}